// Round 5
// baseline (292.470 us; speedup 1.0000x reference)
//
#include <hip/hip_runtime.h>
#include <hip/hip_bf16.h>

// RNN-T joiner: out[b,t,u,v] = sum_k relu(x[b,t,k]+y[b,u,k]) * W[v,k] + bias[v]
// GEMM: M=131072, N=1024, K=512; A generated on the fly.
//
// v4: LDS-intensity fix. Wave tile 64x64 (32 FLOP/LDS-byte = break-even),
// mfma_f32_32x32x16_bf16. Block 64 rows x 512 cols, 8 waves in n, grid
// 2048m x 2n. A staged once full-K (64KB, XOR-swizzled). W bf16 ring
// 2 x 32KB ([col][k32] linear chunks in d_ws -> linear DMA, no swizzle),
// issue-at-top + 2 barriers/step, counted vmcnt(4). Single epilogue per
// block: per-wave LDS transpose -> f32x4 nontemporal full-line stores.

constexpr int Bc = 8, Tc = 256, Uc = 64, Dc = 512, Vc = 1024;
constexpr int BM = 64, BN = 512;
constexpr int KSTEP = 32;
constexpr int NSTEPS = Dc / KSTEP;  // 16
constexpr int BDIM = 512;           // 8 waves, each 64x64 tile

typedef __attribute__((ext_vector_type(8)))  short short8;
typedef __attribute__((ext_vector_type(8)))  unsigned short ushort8;
typedef __attribute__((ext_vector_type(4)))  float f32x4;
typedef __attribute__((ext_vector_type(16))) float f32x16;

#define GLOAD16(g, l) __builtin_amdgcn_global_load_lds( \
    (const __attribute__((address_space(1))) unsigned int*)(g), \
    (__attribute__((address_space(3))) unsigned int*)(l), 16, 0, 0)

__device__ inline unsigned short f2bf(float f) {
    union { float f; unsigned u; } v; v.f = f;
    unsigned r = v.u + 0x7FFFu + ((v.u >> 16) & 1u);  // RNE
    return (unsigned short)(r >> 16);
}

// ---- prep: W fp32 [V][D] -> bf16 [V][D] in d_ws ----
__global__ __launch_bounds__(256) void cvt_w(const float* __restrict__ W,
                                             unsigned short* __restrict__ Wb) {
    const int i = (blockIdx.x * 256 + threadIdx.x) * 8;
    const float4 a = *(const float4*)(W + i);
    const float4 b = *(const float4*)(W + i + 4);
    ushort8 v;
    v[0] = f2bf(a.x); v[1] = f2bf(a.y); v[2] = f2bf(a.z); v[3] = f2bf(a.w);
    v[4] = f2bf(b.x); v[5] = f2bf(b.y); v[6] = f2bf(b.z); v[7] = f2bf(b.w);
    *(ushort8*)(Wb + i) = v;
}

__global__ __launch_bounds__(BDIM) void joiner_v4(
    const float* __restrict__ x, const float* __restrict__ y,
    const unsigned short* __restrict__ Wb, const float* __restrict__ bias,
    float* __restrict__ out)
{
    __shared__ unsigned short As[BM * Dc];         // 64 KB, swizzled, full K
    __shared__ unsigned short Wr[2][BN * KSTEP];   // 2 x 32 KB ring
    __shared__ float Tr[8][16 * 36];               // 18 KB per-wave transpose

    const int tid  = threadIdx.x;
    const int lane = tid & 63;
    const int wid  = tid >> 6;        // 0..7, n-position
    const int l31  = lane & 31;
    const int l32  = lane >> 5;       // 0/1

    const int nhalf = blockIdx.x & 1;
    const int mb    = blockIdx.x >> 1;
    const int bb    = mb >> 8;        // batch
    const int tt    = mb & 255;       // time step
    const int m0    = mb * BM;
    const int n0    = nhalf * BN;

    // bias for this wave's 64 cols (col = n0 + wid*64 + n16*32 + l31)
    const int colg = n0 + wid * 64 + l31;
    float bv[2];
    bv[0] = bias[colg];
    bv[1] = bias[colg + 32];

    // ---- issue W DMA for k-step s into ring buf b (all linear, no swizzle)
    // chunk layout: Wr[b][c*32 + k] for c in [0,512), k in [0,32)
    #define ISSUE_W(s, b)                                                     \
        {                                                                     \
            _Pragma("unroll")                                                 \
            for (int i = 0; i < 4; ++i) {                                     \
                const int d = i * BDIM + tid;   /* 0..2047 slots of 16B */    \
                const int c = d >> 2, ko = d & 3;                             \
                const unsigned short* src =                                   \
                    Wb + (size_t)(n0 + c) * Dc + (s) * KSTEP + ko * 8;        \
                GLOAD16(src, &Wr[b][d * 8]);                                  \
            }                                                                 \
        }

    ISSUE_W(0, 0);

    // ---- stage A = relu(x[b,t,:]+y[b,u,:]) bf16, XOR-swizzled (overlaps DMA0)
    const float* xrow = x + (size_t)(bb * Tc + tt) * Dc;
    #pragma unroll
    for (int i = 0; i < 8; ++i) {
        const int c = tid + i * BDIM;
        const int u = c >> 6;
        const int s = c & 63;
        const float4* xp = (const float4*)(xrow + s * 8);
        const float4* yp = (const float4*)(y + ((size_t)(bb * Uc + u) * Dc + s * 8));
        float4 xa = xp[0], xb = xp[1];
        float4 ya = yp[0], yb = yp[1];
        ushort8 hv;
        hv[0] = f2bf(fmaxf(xa.x + ya.x, 0.f));
        hv[1] = f2bf(fmaxf(xa.y + ya.y, 0.f));
        hv[2] = f2bf(fmaxf(xa.z + ya.z, 0.f));
        hv[3] = f2bf(fmaxf(xa.w + ya.w, 0.f));
        hv[4] = f2bf(fmaxf(xb.x + yb.x, 0.f));
        hv[5] = f2bf(fmaxf(xb.y + yb.y, 0.f));
        hv[6] = f2bf(fmaxf(xb.z + yb.z, 0.f));
        hv[7] = f2bf(fmaxf(xb.w + yb.w, 0.f));
        *(ushort8*)(&As[u * Dc + ((s ^ (u & 7)) * 8)]) = hv;
    }
    asm volatile("s_waitcnt lgkmcnt(0)" ::: "memory");

    f32x16 acc[2][2] = {};  // [m16][n16] 32x32 sub-tiles

    // ---- main loop: 16 k-steps of 32 ----
    #pragma unroll
    for (int s = 0; s < NSTEPS; ++s) {
        // issue next chunk; buf[(s+1)&1] was released by end-barrier of s-1
        if (s + 1 < NSTEPS) ISSUE_W(s + 1, (s + 1) & 1);

        if (s < NSTEPS - 1) asm volatile("s_waitcnt vmcnt(4)" ::: "memory");
        else                asm volatile("s_waitcnt vmcnt(0)" ::: "memory");
        __builtin_amdgcn_sched_barrier(0);
        __builtin_amdgcn_s_barrier();   // all waves' DMA(s) data landed

        // fragments: A row=l31 (+m16*32), k = q*16 + l32*8 + j
        const unsigned short* wp = &Wr[s & 1][0];
        short8 af[2][2], wf[2][2];  // [q][m16/n16]
        #pragma unroll
        for (int q = 0; q < 2; ++q) {
            const int oA = s * 4 + q * 2 + l32;  // A octet index (0..63)
            #pragma unroll
            for (int m16 = 0; m16 < 2; ++m16) {
                const int r = m16 * 32 + l31;
                af[q][m16] = *(const short8*)(&As[r * Dc + ((oA ^ (r & 7)) * 8)]);
            }
            #pragma unroll
            for (int n16 = 0; n16 < 2; ++n16) {
                const int vr = wid * 64 + n16 * 32 + l31;
                wf[q][n16] = *(const short8*)(wp + vr * KSTEP + q * 16 + l32 * 8);
            }
        }
        __builtin_amdgcn_s_setprio(1);
        #pragma unroll
        for (int q = 0; q < 2; ++q)
            #pragma unroll
            for (int m16 = 0; m16 < 2; ++m16)
                #pragma unroll
                for (int n16 = 0; n16 < 2; ++n16)
                    acc[m16][n16] = __builtin_amdgcn_mfma_f32_32x32x16_bf16(
                        af[q][m16], wf[q][n16], acc[m16][n16], 0, 0, 0);
        __builtin_amdgcn_s_setprio(0);

        // release buf[s&1] for the issue at top of step s+1
        if (s < NSTEPS - 1) __builtin_amdgcn_s_barrier();
    }

    // ---- epilogue: C/D (32x32): col=l31, row=(reg&3)+8*(reg>>2)+4*l32 ----
    // per-wave transpose in Tr (16 rows x stride 36), f32x4 full-line stores
    float* tr = &Tr[wid][0];
    #pragma unroll
    for (int m16 = 0; m16 < 2; ++m16) {
        #pragma unroll
        for (int n16 = 0; n16 < 2; ++n16) {
            #pragma unroll
            for (int h = 0; h < 2; ++h) {   // regs h*8..h*8+7 -> rows h*16..h*16+15
                #pragma unroll
                for (int e = 0; e < 8; ++e) {
                    const int rl = (e & 3) + 8 * (e >> 2) + 4 * l32;  // 0..15
                    tr[rl * 36 + l31] = acc[m16][n16][h * 8 + e] + bv[n16];
                }
                #pragma unroll
                for (int h2 = 0; h2 < 2; ++h2) {
                    const int rr = h2 * 8 + (lane >> 3);   // 0..15
                    const int c4 = (lane & 7) * 4;         // 0..28
                    f32x4 o;
                    o[0] = tr[rr * 36 + c4 + 0];
                    o[1] = tr[rr * 36 + c4 + 1];
                    o[2] = tr[rr * 36 + c4 + 2];
                    o[3] = tr[rr * 36 + c4 + 3];
                    const size_t off =
                        (size_t)(m0 + m16 * 32 + h * 16 + rr) * Vc
                        + n0 + wid * 64 + n16 * 32 + c4;
                    __builtin_nontemporal_store(o, (f32x4*)(out + off));
                }
            }
        }
    }
    #undef ISSUE_W
}

// ---- round-1 fallback (only if ws_size < 1MB) ----
constexpr int F_BM = 128, F_BN = 128, F_BK = 64;
constexpr int F_MT = (Bc * Tc * Uc) / F_BM;
constexpr int F_NT = Vc / F_BN;

__global__ __launch_bounds__(256) void joiner_mfma(
    const float* __restrict__ x, const float* __restrict__ y,
    const float* __restrict__ W, const float* __restrict__ bias,
    float* __restrict__ out)
{
    __shared__ unsigned short As[F_BM * F_BK];
    __shared__ unsigned short Wsh[F_BN * F_BK];
    const int tid = threadIdx.x;
    const int mtile = blockIdx.x % F_MT;
    const int ntile = blockIdx.x / F_MT;
    const int m0 = mtile * F_BM, v0 = ntile * F_BN;
    const int bb = m0 / (Tc * Uc);
    const int t0 = (m0 % (Tc * Uc)) / Uc;
    const int lane = tid & 63, wid = tid >> 6;
    const int wm = wid >> 1, wn = wid & 1;
    const int lr = lane & 15, lk8 = lane >> 4;
    f32x4 acc[4][4] = {};
    for (int k0 = 0; k0 < Dc; k0 += F_BK) {
        __syncthreads();
        #pragma unroll
        for (int i = 0; i < 4; ++i) {
            const int chunk = tid + i * 256;
            const int row = chunk >> 3, slot = chunk & 7;
            const int ps8 = (slot ^ (row & 7)) * 8;
            const int t = t0 + (row >> 6), u = row & 63;
            const float4* xp = (const float4*)(x + ((size_t)(bb * Tc + t) * Dc + k0 + slot * 8));
            const float4* yp = (const float4*)(y + ((size_t)(bb * Uc + u) * Dc + k0 + slot * 8));
            float4 xa = xp[0], xb2 = xp[1], ya = yp[0], yb2 = yp[1];
            ushort8 hv;
            hv[0] = f2bf(fmaxf(xa.x + ya.x, 0.f)); hv[1] = f2bf(fmaxf(xa.y + ya.y, 0.f));
            hv[2] = f2bf(fmaxf(xa.z + ya.z, 0.f)); hv[3] = f2bf(fmaxf(xa.w + ya.w, 0.f));
            hv[4] = f2bf(fmaxf(xb2.x + yb2.x, 0.f)); hv[5] = f2bf(fmaxf(xb2.y + yb2.y, 0.f));
            hv[6] = f2bf(fmaxf(xb2.z + yb2.z, 0.f)); hv[7] = f2bf(fmaxf(xb2.w + yb2.w, 0.f));
            *(ushort8*)(&As[row * F_BK + ps8]) = hv;
            const float4* wp = (const float4*)(W + ((size_t)(v0 + row) * Dc + k0 + slot * 8));
            float4 wa = wp[0], wb2 = wp[1];
            ushort8 wv;
            wv[0] = f2bf(wa.x); wv[1] = f2bf(wa.y); wv[2] = f2bf(wa.z); wv[3] = f2bf(wa.w);
            wv[4] = f2bf(wb2.x); wv[5] = f2bf(wb2.y); wv[6] = f2bf(wb2.z); wv[7] = f2bf(wb2.w);
            *(ushort8*)(&Wsh[row * F_BK + ps8]) = wv;
        }
        __syncthreads();
        #pragma unroll
        for (int kk = 0; kk < 2; ++kk) {
            const int psk = kk * 4 + lk8;
            short8 af[4], bfr[4];
            #pragma unroll
            for (int mf = 0; mf < 4; ++mf) {
                const int row = wm * 64 + mf * 16 + lr;
                af[mf] = *(const short8*)(&As[row * F_BK + ((psk ^ (row & 7)) * 8)]);
            }
            #pragma unroll
            for (int nf = 0; nf < 4; ++nf) {
                const int row = wn * 64 + nf * 16 + lr;
                bfr[nf] = *(const short8*)(&Wsh[row * F_BK + ((psk ^ (row & 7)) * 8)]);
            }
            #pragma unroll
            for (int mf = 0; mf < 4; ++mf)
                #pragma unroll
                for (int nf = 0; nf < 4; ++nf)
                    acc[mf][nf] = __builtin_amdgcn_mfma_f32_16x16x32_bf16(af[mf], bfr[nf], acc[mf][nf], 0, 0, 0);
        }
    }
    #pragma unroll
    for (int nf = 0; nf < 4; ++nf) {
        const int v = v0 + wn * 64 + nf * 16 + lr;
        const float bv = bias[v];
        #pragma unroll
        for (int mf = 0; mf < 4; ++mf) {
            const int mrow = m0 + wm * 64 + mf * 16 + (lane >> 4) * 4;
            #pragma unroll
            for (int j = 0; j < 4; ++j)
                out[(size_t)(mrow + j) * Vc + v] = acc[mf][nf][j] + bv;
        }
    }
}

extern "C" void kernel_launch(void* const* d_in, const int* in_sizes, int n_in,
                              void* d_out, int out_size, void* d_ws, size_t ws_size,
                              hipStream_t stream) {
    const float* x = (const float*)d_in[0];
    const float* y = (const float*)d_in[1];
    const float* W = (const float*)d_in[2];
    const float* b = (const float*)d_in[3];
    float* out = (float*)d_out;

    const size_t w_bytes = (size_t)Vc * Dc * sizeof(unsigned short);  // 1 MB
    if (ws_size >= w_bytes) {
        unsigned short* Wb = (unsigned short*)d_ws;
        cvt_w<<<dim3((Vc * Dc) / (256 * 8)), 256, 0, stream>>>(W, Wb);
        joiner_v4<<<dim3((Bc * Tc * Uc / BM) * (Vc / BN)), BDIM, 0, stream>>>(x, y, Wb, b, out);
    } else {
        joiner_mfma<<<dim3(F_MT * F_NT), 256, 0, stream>>>(x, y, W, b, out);
    }
}

// Round 6
// 284.847 us; speedup vs baseline: 1.0268x; 1.0268x over previous
//
#include <hip/hip_runtime.h>
#include <hip/hip_bf16.h>

// RNN-T joiner: out[b,t,u,v] = sum_k relu(x[b,t,k]+y[b,u,k]) * W[v,k] + bias[v]
// GEMM: M=131072, N=1024, K=512; A generated on the fly.
//
// v5 = v4 + conflict-free W LDS mapping (the 35.6M bank conflicts were the
// [col][k] 64B-row-stride W reads: 16-way). New mapping: DMA slot d holds
// (col=d>>2, oct=(d&3)^((col>>1)&3)) -> source stays 64B-line coalesced,
// read offset col*64+((oct^((col>>1)&3))*16) spreads 32 lanes over all 8
// 16B slots mod 128 -> balanced, conflict-free. Rest unchanged from v4:
// wave tile 64x64 (mfma_32x32x16), A staged once full-K (swizzled), W ring
// 2x32KB counted vmcnt(4), setprio around MFMA, transpose epilogue with
// full-128B f32x4 nontemporal stores.

constexpr int Bc = 8, Tc = 256, Uc = 64, Dc = 512, Vc = 1024;
constexpr int BM = 64, BN = 512;
constexpr int KSTEP = 32;
constexpr int NSTEPS = Dc / KSTEP;  // 16
constexpr int BDIM = 512;           // 8 waves, each 64x64 tile

typedef __attribute__((ext_vector_type(8)))  short short8;
typedef __attribute__((ext_vector_type(8)))  unsigned short ushort8;
typedef __attribute__((ext_vector_type(4)))  float f32x4;
typedef __attribute__((ext_vector_type(16))) float f32x16;

#define GLOAD16(g, l) __builtin_amdgcn_global_load_lds( \
    (const __attribute__((address_space(1))) unsigned int*)(g), \
    (__attribute__((address_space(3))) unsigned int*)(l), 16, 0, 0)

__device__ inline unsigned short f2bf(float f) {
    union { float f; unsigned u; } v; v.f = f;
    unsigned r = v.u + 0x7FFFu + ((v.u >> 16) & 1u);  // RNE
    return (unsigned short)(r >> 16);
}

// ---- prep: W fp32 [V][D] -> bf16 [V][D] in d_ws ----
__global__ __launch_bounds__(256) void cvt_w(const float* __restrict__ W,
                                             unsigned short* __restrict__ Wb) {
    const int i = (blockIdx.x * 256 + threadIdx.x) * 8;
    const float4 a = *(const float4*)(W + i);
    const float4 b = *(const float4*)(W + i + 4);
    ushort8 v;
    v[0] = f2bf(a.x); v[1] = f2bf(a.y); v[2] = f2bf(a.z); v[3] = f2bf(a.w);
    v[4] = f2bf(b.x); v[5] = f2bf(b.y); v[6] = f2bf(b.z); v[7] = f2bf(b.w);
    *(ushort8*)(Wb + i) = v;
}

__global__ __launch_bounds__(BDIM) void joiner_v5(
    const float* __restrict__ x, const float* __restrict__ y,
    const unsigned short* __restrict__ Wb, const float* __restrict__ bias,
    float* __restrict__ out)
{
    __shared__ unsigned short As[BM * Dc];         // 64 KB, swizzled, full K
    __shared__ unsigned short Wr[2][BN * KSTEP];   // 2 x 32 KB ring
    __shared__ float Tr[8][16 * 36];               // 18 KB per-wave transpose

    const int tid  = threadIdx.x;
    const int lane = tid & 63;
    const int wid  = tid >> 6;        // 0..7, n-position
    const int l31  = lane & 31;
    const int l32  = lane >> 5;       // 0/1

    const int nhalf = blockIdx.x & 1;
    const int mb    = blockIdx.x >> 1;
    const int bb    = mb >> 8;        // batch
    const int tt    = mb & 255;       // time step
    const int m0    = mb * BM;
    const int n0    = nhalf * BN;

    // bias for this wave's 64 cols (col = n0 + wid*64 + n16*32 + l31)
    const int colg = n0 + wid * 64 + l31;
    float bv[2];
    bv[0] = bias[colg];
    bv[1] = bias[colg + 32];

    // ---- issue W DMA for k-step s into ring buf b.
    // slot d (16B) holds (col=d>>2, oct=(d&3)^((col>>1)&3)):
    //  - source: 4 consecutive slots cover one full 64B line (coalesced)
    //  - read (col,o) at elem off col*32 + (o^((col>>1)&3))*8: 32 lanes hit
    //    all 8 16B-slots mod 128 -> bank-balanced, conflict-free.
    #define ISSUE_W(s, b)                                                     \
        {                                                                     \
            _Pragma("unroll")                                                 \
            for (int i = 0; i < 4; ++i) {                                     \
                const int d = i * BDIM + tid;   /* 0..2047 slots of 16B */    \
                const int c = d >> 2, j = d & 3;                              \
                const int oct = j ^ ((c >> 1) & 3);                           \
                const unsigned short* src =                                   \
                    Wb + (size_t)(n0 + c) * Dc + (s) * KSTEP + oct * 8;       \
                GLOAD16(src, &Wr[b][d * 8]);                                  \
            }                                                                 \
        }

    ISSUE_W(0, 0);

    // ---- stage A = relu(x[b,t,:]+y[b,u,:]) bf16, XOR-swizzled (overlaps DMA0)
    const float* xrow = x + (size_t)(bb * Tc + tt) * Dc;
    #pragma unroll
    for (int i = 0; i < 8; ++i) {
        const int c = tid + i * BDIM;
        const int u = c >> 6;
        const int s = c & 63;
        const float4* xp = (const float4*)(xrow + s * 8);
        const float4* yp = (const float4*)(y + ((size_t)(bb * Uc + u) * Dc + s * 8));
        float4 xa = xp[0], xb = xp[1];
        float4 ya = yp[0], yb = yp[1];
        ushort8 hv;
        hv[0] = f2bf(fmaxf(xa.x + ya.x, 0.f));
        hv[1] = f2bf(fmaxf(xa.y + ya.y, 0.f));
        hv[2] = f2bf(fmaxf(xa.z + ya.z, 0.f));
        hv[3] = f2bf(fmaxf(xa.w + ya.w, 0.f));
        hv[4] = f2bf(fmaxf(xb.x + yb.x, 0.f));
        hv[5] = f2bf(fmaxf(xb.y + yb.y, 0.f));
        hv[6] = f2bf(fmaxf(xb.z + yb.z, 0.f));
        hv[7] = f2bf(fmaxf(xb.w + yb.w, 0.f));
        *(ushort8*)(&As[u * Dc + ((s ^ (u & 7)) * 8)]) = hv;
    }
    asm volatile("s_waitcnt lgkmcnt(0)" ::: "memory");

    f32x16 acc[2][2] = {};  // [m16][n16] 32x32 sub-tiles

    // ---- main loop: 16 k-steps of 32 ----
    #pragma unroll
    for (int s = 0; s < NSTEPS; ++s) {
        // issue next chunk; buf[(s+1)&1] was released by end-barrier of s-1
        if (s + 1 < NSTEPS) ISSUE_W(s + 1, (s + 1) & 1);

        if (s < NSTEPS - 1) asm volatile("s_waitcnt vmcnt(4)" ::: "memory");
        else                asm volatile("s_waitcnt vmcnt(0)" ::: "memory");
        __builtin_amdgcn_sched_barrier(0);
        __builtin_amdgcn_s_barrier();   // all waves' DMA(s) data landed

        // fragments: A row=l31 (+m16*32), k = q*16 + l32*8 + j
        const unsigned short* wp = &Wr[s & 1][0];
        short8 af[2][2], wf[2][2];  // [q][m16/n16]
        #pragma unroll
        for (int q = 0; q < 2; ++q) {
            const int oA = s * 4 + q * 2 + l32;  // A octet index (0..63)
            #pragma unroll
            for (int m16 = 0; m16 < 2; ++m16) {
                const int r = m16 * 32 + l31;
                af[q][m16] = *(const short8*)(&As[r * Dc + ((oA ^ (r & 7)) * 8)]);
            }
            const int o = q * 2 + l32;           // W octet within chunk (0..3)
            #pragma unroll
            for (int n16 = 0; n16 < 2; ++n16) {
                const int vr = wid * 64 + n16 * 32 + l31;   // local col
                const int oo = o ^ ((vr >> 1) & 3);
                wf[q][n16] = *(const short8*)(wp + vr * KSTEP + oo * 8);
            }
        }
        __builtin_amdgcn_s_setprio(1);
        #pragma unroll
        for (int q = 0; q < 2; ++q)
            #pragma unroll
            for (int m16 = 0; m16 < 2; ++m16)
                #pragma unroll
                for (int n16 = 0; n16 < 2; ++n16)
                    acc[m16][n16] = __builtin_amdgcn_mfma_f32_32x32x16_bf16(
                        af[q][m16], wf[q][n16], acc[m16][n16], 0, 0, 0);
        __builtin_amdgcn_s_setprio(0);

        // release buf[s&1] for the issue at top of step s+1
        if (s < NSTEPS - 1) __builtin_amdgcn_s_barrier();
    }

    // ---- epilogue: C/D (32x32): col=l31, row=(reg&3)+8*(reg>>2)+4*l32 ----
    // per-wave transpose in Tr (16 rows x stride 36), f32x4 full-line stores
    float* tr = &Tr[wid][0];
    #pragma unroll
    for (int m16 = 0; m16 < 2; ++m16) {
        #pragma unroll
        for (int n16 = 0; n16 < 2; ++n16) {
            #pragma unroll
            for (int h = 0; h < 2; ++h) {   // regs h*8..h*8+7 -> rows h*16..h*16+15
                #pragma unroll
                for (int e = 0; e < 8; ++e) {
                    const int rl = (e & 3) + 8 * (e >> 2) + 4 * l32;  // 0..15
                    tr[rl * 36 + l31] = acc[m16][n16][h * 8 + e] + bv[n16];
                }
                #pragma unroll
                for (int h2 = 0; h2 < 2; ++h2) {
                    const int rr = h2 * 8 + (lane >> 3);   // 0..15
                    const int c4 = (lane & 7) * 4;         // 0..28
                    f32x4 o;
                    o[0] = tr[rr * 36 + c4 + 0];
                    o[1] = tr[rr * 36 + c4 + 1];
                    o[2] = tr[rr * 36 + c4 + 2];
                    o[3] = tr[rr * 36 + c4 + 3];
                    const size_t off =
                        (size_t)(m0 + m16 * 32 + h * 16 + rr) * Vc
                        + n0 + wid * 64 + n16 * 32 + c4;
                    __builtin_nontemporal_store(o, (f32x4*)(out + off));
                }
            }
        }
    }
    #undef ISSUE_W
}

// ---- round-1 fallback (only if ws_size < 1MB) ----
constexpr int F_BM = 128, F_BN = 128, F_BK = 64;
constexpr int F_MT = (Bc * Tc * Uc) / F_BM;
constexpr int F_NT = Vc / F_BN;

__global__ __launch_bounds__(256) void joiner_mfma(
    const float* __restrict__ x, const float* __restrict__ y,
    const float* __restrict__ W, const float* __restrict__ bias,
    float* __restrict__ out)
{
    __shared__ unsigned short As[F_BM * F_BK];
    __shared__ unsigned short Wsh[F_BN * F_BK];
    const int tid = threadIdx.x;
    const int mtile = blockIdx.x % F_MT;
    const int ntile = blockIdx.x / F_MT;
    const int m0 = mtile * F_BM, v0 = ntile * F_BN;
    const int bb = m0 / (Tc * Uc);
    const int t0 = (m0 % (Tc * Uc)) / Uc;
    const int lane = tid & 63, wid = tid >> 6;
    const int wm = wid >> 1, wn = wid & 1;
    const int lr = lane & 15, lk8 = lane >> 4;
    f32x4 acc[4][4] = {};
    for (int k0 = 0; k0 < Dc; k0 += F_BK) {
        __syncthreads();
        #pragma unroll
        for (int i = 0; i < 4; ++i) {
            const int chunk = tid + i * 256;
            const int row = chunk >> 3, slot = chunk & 7;
            const int ps8 = (slot ^ (row & 7)) * 8;
            const int t = t0 + (row >> 6), u = row & 63;
            const float4* xp = (const float4*)(x + ((size_t)(bb * Tc + t) * Dc + k0 + slot * 8));
            const float4* yp = (const float4*)(y + ((size_t)(bb * Uc + u) * Dc + k0 + slot * 8));
            float4 xa = xp[0], xb2 = xp[1], ya = yp[0], yb2 = yp[1];
            ushort8 hv;
            hv[0] = f2bf(fmaxf(xa.x + ya.x, 0.f)); hv[1] = f2bf(fmaxf(xa.y + ya.y, 0.f));
            hv[2] = f2bf(fmaxf(xa.z + ya.z, 0.f)); hv[3] = f2bf(fmaxf(xa.w + ya.w, 0.f));
            hv[4] = f2bf(fmaxf(xb2.x + yb2.x, 0.f)); hv[5] = f2bf(fmaxf(xb2.y + yb2.y, 0.f));
            hv[6] = f2bf(fmaxf(xb2.z + yb2.z, 0.f)); hv[7] = f2bf(fmaxf(xb2.w + yb2.w, 0.f));
            *(ushort8*)(&As[row * F_BK + ps8]) = hv;
            const float4* wp = (const float4*)(W + ((size_t)(v0 + row) * Dc + k0 + slot * 8));
            float4 wa = wp[0], wb2 = wp[1];
            ushort8 wv;
            wv[0] = f2bf(wa.x); wv[1] = f2bf(wa.y); wv[2] = f2bf(wa.z); wv[3] = f2bf(wa.w);
            wv[4] = f2bf(wb2.x); wv[5] = f2bf(wb2.y); wv[6] = f2bf(wb2.z); wv[7] = f2bf(wb2.w);
            *(ushort8*)(&Wsh[row * F_BK + ps8]) = wv;
        }
        __syncthreads();
        #pragma unroll
        for (int kk = 0; kk < 2; ++kk) {
            const int psk = kk * 4 + lk8;
            short8 af[4], bfr[4];
            #pragma unroll
            for (int mf = 0; mf < 4; ++mf) {
                const int row = wm * 64 + mf * 16 + lr;
                af[mf] = *(const short8*)(&As[row * F_BK + ((psk ^ (row & 7)) * 8)]);
            }
            #pragma unroll
            for (int nf = 0; nf < 4; ++nf) {
                const int row = wn * 64 + nf * 16 + lr;
                bfr[nf] = *(const short8*)(&Wsh[row * F_BK + ((psk ^ (row & 7)) * 8)]);
            }
            #pragma unroll
            for (int mf = 0; mf < 4; ++mf)
                #pragma unroll
                for (int nf = 0; nf < 4; ++nf)
                    acc[mf][nf] = __builtin_amdgcn_mfma_f32_16x16x32_bf16(af[mf], bfr[nf], acc[mf][nf], 0, 0, 0);
        }
    }
    #pragma unroll
    for (int nf = 0; nf < 4; ++nf) {
        const int v = v0 + wn * 64 + nf * 16 + lr;
        const float bv = bias[v];
        #pragma unroll
        for (int mf = 0; mf < 4; ++mf) {
            const int mrow = m0 + wm * 64 + mf * 16 + (lane >> 4) * 4;
            #pragma unroll
            for (int j = 0; j < 4; ++j)
                out[(size_t)(mrow + j) * Vc + v] = acc[mf][nf][j] + bv;
        }
    }
}

extern "C" void kernel_launch(void* const* d_in, const int* in_sizes, int n_in,
                              void* d_out, int out_size, void* d_ws, size_t ws_size,
                              hipStream_t stream) {
    const float* x = (const float*)d_in[0];
    const float* y = (const float*)d_in[1];
    const float* W = (const float*)d_in[2];
    const float* b = (const float*)d_in[3];
    float* out = (float*)d_out;

    const size_t w_bytes = (size_t)Vc * Dc * sizeof(unsigned short);  // 1 MB
    if (ws_size >= w_bytes) {
        unsigned short* Wb = (unsigned short*)d_ws;
        cvt_w<<<dim3((Vc * Dc) / (256 * 8)), 256, 0, stream>>>(W, Wb);
        joiner_v5<<<dim3((Bc * Tc * Uc / BM) * (Vc / BN)), BDIM, 0, stream>>>(x, y, Wb, b, out);
    } else {
        joiner_mfma<<<dim3(F_MT * F_NT), 256, 0, stream>>>(x, y, W, b, out);
    }
}

// Round 7
// 201.539 us; speedup vs baseline: 1.4512x; 1.4134x over previous
//
#include <hip/hip_runtime.h>
#include <hip/hip_bf16.h>

// RNN-T joiner: out[b,t,u,v] = sum_k relu(x[b,t,k]+y[b,u,k]) * W[v,k] + bias[v]
// GEMM: M=131072, N=1024, K=512; A generated on the fly.
//
// v6: barrier-free k-loop, occupancy fix.
//  - A staged once/block in 64KB LDS (XOR-swizzled), the ONLY LDS user.
//    Epilogue transpose buffer overlaid on As after a syncthreads.
//    LDS/block = 64KB -> 2 blocks/CU; __launch_bounds__(512,4) -> <=128 VGPR
//    -> 16 waves/CU free-running (no per-step barriers at all).
//  - W pre-transposed in d_ws to [koct>>1][col][koct&1] 16B-chunk layout:
//    a wave's B-frag global load = one contiguous 1KB segment (L2-resident,
//    FETCH stays ~10MB). Registers double-buffered (named bufs, depth 1),
//    compiler inserts precise counted vmcnt (no barrier -> no drain).
//  - Wave tile 64x64 via mfma_f32_32x32x16_bf16 (mapping verified in v5).
//  - Epilogue: per-wave LDS transpose -> f32x4 nontemporal full-line stores
//    (verified 524MB WRITE_SIZE in v5).

constexpr int Bc = 8, Tc = 256, Uc = 64, Dc = 512, Vc = 1024;
constexpr int BM = 64, BN = 512;
constexpr int NSTEPS = 16;   // K=512 in steps of 32
constexpr int BDIM = 512;    // 8 waves, side by side in n

typedef __attribute__((ext_vector_type(8)))  short short8;
typedef __attribute__((ext_vector_type(8)))  unsigned short ushort8;
typedef __attribute__((ext_vector_type(4)))  float f32x4;
typedef __attribute__((ext_vector_type(16))) float f32x16;

__device__ inline unsigned short f2bf(float f) {
    union { float f; unsigned u; } v; v.f = f;
    unsigned r = v.u + 0x7FFFu + ((v.u >> 16) & 1u);  // RNE
    return (unsigned short)(r >> 16);
}

// ---- prep: W fp32 [V][D] -> bf16 chunk layout Wt[(koct>>1)*2048 + v*2 + (koct&1)]
// (16B chunks; koct = k/8). Wave reads one v-row (2KB contiguous) -> coalesced.
__global__ __launch_bounds__(256) void cvt_wt(const float* __restrict__ W,
                                              unsigned short* __restrict__ Wt) {
    const int idx  = blockIdx.x * 256 + threadIdx.x;  // 65536 total
    const int v    = idx >> 6;
    const int koct = idx & 63;
    const float4 a = *(const float4*)(W + (size_t)v * Dc + koct * 8);
    const float4 b = *(const float4*)(W + (size_t)v * Dc + koct * 8 + 4);
    ushort8 o;
    o[0] = f2bf(a.x); o[1] = f2bf(a.y); o[2] = f2bf(a.z); o[3] = f2bf(a.w);
    o[4] = f2bf(b.x); o[5] = f2bf(b.y); o[6] = f2bf(b.z); o[7] = f2bf(b.w);
    const size_t chunk = (size_t)(koct >> 1) * 2048 + v * 2 + (koct & 1);
    *(ushort8*)(Wt + chunk * 8) = o;
}

__global__ __launch_bounds__(BDIM, 4) void joiner_v6(
    const float* __restrict__ x, const float* __restrict__ y,
    const unsigned short* __restrict__ Wt, const float* __restrict__ bias,
    float* __restrict__ out)
{
    __shared__ __align__(16) unsigned char smem[BM * Dc * 2];  // 64 KB
    unsigned short* As = (unsigned short*)smem;                 // k-loop use
    // epilogue overlays per-wave transpose pads on the same memory

    const int tid  = threadIdx.x;
    const int lane = tid & 63;
    const int wid  = tid >> 6;        // 0..7, n-position
    const int l31  = lane & 31;
    const int l32  = lane >> 5;       // 0/1

    const int nhalf = blockIdx.x & 1;
    const int mb    = blockIdx.x >> 1;
    const int bb    = mb >> 8;        // batch
    const int tt    = mb & 255;       // time step
    const int m0    = mb * BM;
    const int n0    = nhalf * BN;
    const int colbase = n0 + wid * 64;

    float bv[2];
    bv[0] = bias[colbase + l31];
    bv[1] = bias[colbase + 32 + l31];

    // ---- stage A = relu(x[b,t,:]+y[b,u,:]) bf16, XOR-swizzled ----
    const float* xrow = x + (size_t)(bb * Tc + tt) * Dc;
    #pragma unroll
    for (int i = 0; i < 8; ++i) {
        const int c = tid + i * BDIM;
        const int u = c >> 6;
        const int s = c & 63;
        const float4* xp = (const float4*)(xrow + s * 8);
        const float4* yp = (const float4*)(y + ((size_t)(bb * Uc + u) * Dc + s * 8));
        float4 xa = xp[0], xb = xp[1];
        float4 ya = yp[0], yb = yp[1];
        ushort8 hv;
        hv[0] = f2bf(fmaxf(xa.x + ya.x, 0.f));
        hv[1] = f2bf(fmaxf(xa.y + ya.y, 0.f));
        hv[2] = f2bf(fmaxf(xa.z + ya.z, 0.f));
        hv[3] = f2bf(fmaxf(xa.w + ya.w, 0.f));
        hv[4] = f2bf(fmaxf(xb.x + yb.x, 0.f));
        hv[5] = f2bf(fmaxf(xb.y + yb.y, 0.f));
        hv[6] = f2bf(fmaxf(xb.z + yb.z, 0.f));
        hv[7] = f2bf(fmaxf(xb.w + yb.w, 0.f));
        *(ushort8*)(&As[u * Dc + ((s ^ (u & 7)) * 8)]) = hv;
    }
    __syncthreads();

    // ---- W frag base: chunk (ks*2+q)*2048 + col*2 + l32, col = colbase+n16*32+l31
    // per-lane base covers the (2*l31+l32) part; (ks,q,n16) are constant offsets.
    const unsigned short* pW = Wt + (size_t)(colbase * 2 + 2 * l31 + l32) * 8;

    f32x16 acc[2][2] = {};  // [m16][n16] 32x32 sub-tiles
    short8 wfA[2][2], wfB[2][2];  // [q][n16] named double-buffer (rule 20)

    #define LOADW(buf, ks)                                                    \
        {                                                                     \
            _Pragma("unroll")                                                 \
            for (int q = 0; q < 2; ++q)                                       \
                _Pragma("unroll")                                             \
                for (int n16 = 0; n16 < 2; ++n16)                             \
                    buf[q][n16] = *(const short8*)(pW + ((ks) * 2 + q) * 16384 \
                                                   + n16 * 512);              \
        }

    // one k-step: prefetch (ks+1) into nxt, compute ks from cur
    #define STEP(cur, nxt, ks)                                                \
        {                                                                     \
            if ((ks) + 1 < NSTEPS) LOADW(nxt, (ks) + 1);                      \
            _Pragma("unroll")                                                 \
            for (int q = 0; q < 2; ++q) {                                     \
                const int oA = (ks) * 4 + q * 2 + l32;                        \
                short8 af0 = *(const short8*)(&As[l31 * Dc                    \
                                              + ((oA ^ (l31 & 7)) * 8)]);     \
                short8 af1 = *(const short8*)(&As[(32 + l31) * Dc             \
                                              + ((oA ^ (l31 & 7)) * 8)]);     \
                __builtin_amdgcn_s_setprio(1);                                \
                acc[0][0] = __builtin_amdgcn_mfma_f32_32x32x16_bf16(          \
                    af0, cur[q][0], acc[0][0], 0, 0, 0);                      \
                acc[0][1] = __builtin_amdgcn_mfma_f32_32x32x16_bf16(          \
                    af0, cur[q][1], acc[0][1], 0, 0, 0);                      \
                acc[1][0] = __builtin_amdgcn_mfma_f32_32x32x16_bf16(          \
                    af1, cur[q][0], acc[1][0], 0, 0, 0);                      \
                acc[1][1] = __builtin_amdgcn_mfma_f32_32x32x16_bf16(          \
                    af1, cur[q][1], acc[1][1], 0, 0, 0);                      \
                __builtin_amdgcn_s_setprio(0);                                \
            }                                                                 \
        }

    LOADW(wfA, 0);
    #pragma unroll
    for (int ks = 0; ks < NSTEPS; ks += 2) {
        STEP(wfA, wfB, ks);
        STEP(wfB, wfA, ks + 1);
    }
    #undef STEP
    #undef LOADW

    // ---- epilogue: overlay Tr on As space (all A reads done) ----
    __syncthreads();
    float* tr = (float*)smem + wid * (16 * 36);  // 2.3KB per wave, 18.4KB total
    #pragma unroll
    for (int m16 = 0; m16 < 2; ++m16) {
        #pragma unroll
        for (int n16 = 0; n16 < 2; ++n16) {
            #pragma unroll
            for (int h = 0; h < 2; ++h) {   // regs h*8..h*8+7 -> rows h*16..+15
                #pragma unroll
                for (int e = 0; e < 8; ++e) {
                    const int rl = (e & 3) + 8 * (e >> 2) + 4 * l32;  // 0..15
                    tr[rl * 36 + l31] = acc[m16][n16][h * 8 + e] + bv[n16];
                }
                #pragma unroll
                for (int h2 = 0; h2 < 2; ++h2) {
                    const int rr = h2 * 8 + (lane >> 3);   // 0..15
                    const int c4 = (lane & 7) * 4;         // 0..28
                    f32x4 o;
                    o[0] = tr[rr * 36 + c4 + 0];
                    o[1] = tr[rr * 36 + c4 + 1];
                    o[2] = tr[rr * 36 + c4 + 2];
                    o[3] = tr[rr * 36 + c4 + 3];
                    const size_t off =
                        (size_t)(m0 + m16 * 32 + h * 16 + rr) * Vc
                        + colbase + n16 * 32 + c4;
                    __builtin_nontemporal_store(o, (f32x4*)(out + off));
                }
            }
        }
    }
}

// ---- round-1 fallback (only if ws_size < 1MB) ----
constexpr int F_BM = 128, F_BN = 128, F_BK = 64;
constexpr int F_MT = (Bc * Tc * Uc) / F_BM;
constexpr int F_NT = Vc / F_BN;

__global__ __launch_bounds__(256) void joiner_mfma(
    const float* __restrict__ x, const float* __restrict__ y,
    const float* __restrict__ W, const float* __restrict__ bias,
    float* __restrict__ out)
{
    __shared__ unsigned short As[F_BM * F_BK];
    __shared__ unsigned short Wsh[F_BN * F_BK];
    const int tid = threadIdx.x;
    const int mtile = blockIdx.x % F_MT;
    const int ntile = blockIdx.x / F_MT;
    const int m0 = mtile * F_BM, v0 = ntile * F_BN;
    const int bb = m0 / (Tc * Uc);
    const int t0 = (m0 % (Tc * Uc)) / Uc;
    const int lane = tid & 63, wid = tid >> 6;
    const int wm = wid >> 1, wn = wid & 1;
    const int lr = lane & 15, lk8 = lane >> 4;
    f32x4 acc[4][4] = {};
    for (int k0 = 0; k0 < Dc; k0 += F_BK) {
        __syncthreads();
        #pragma unroll
        for (int i = 0; i < 4; ++i) {
            const int chunk = tid + i * 256;
            const int row = chunk >> 3, slot = chunk & 7;
            const int ps8 = (slot ^ (row & 7)) * 8;
            const int t = t0 + (row >> 6), u = row & 63;
            const float4* xp = (const float4*)(x + ((size_t)(bb * Tc + t) * Dc + k0 + slot * 8));
            const float4* yp = (const float4*)(y + ((size_t)(bb * Uc + u) * Dc + k0 + slot * 8));
            float4 xa = xp[0], xb2 = xp[1], ya = yp[0], yb2 = yp[1];
            ushort8 hv;
            hv[0] = f2bf(fmaxf(xa.x + ya.x, 0.f)); hv[1] = f2bf(fmaxf(xa.y + ya.y, 0.f));
            hv[2] = f2bf(fmaxf(xa.z + ya.z, 0.f)); hv[3] = f2bf(fmaxf(xa.w + ya.w, 0.f));
            hv[4] = f2bf(fmaxf(xb2.x + yb2.x, 0.f)); hv[5] = f2bf(fmaxf(xb2.y + yb2.y, 0.f));
            hv[6] = f2bf(fmaxf(xb2.z + yb2.z, 0.f)); hv[7] = f2bf(fmaxf(xb2.w + yb2.w, 0.f));
            *(ushort8*)(&As[row * F_BK + ps8]) = hv;
            const float4* wp = (const float4*)(W + ((size_t)(v0 + row) * Dc + k0 + slot * 8));
            float4 wa = wp[0], wb2 = wp[1];
            ushort8 wv;
            wv[0] = f2bf(wa.x); wv[1] = f2bf(wa.y); wv[2] = f2bf(wa.z); wv[3] = f2bf(wa.w);
            wv[4] = f2bf(wb2.x); wv[5] = f2bf(wb2.y); wv[6] = f2bf(wb2.z); wv[7] = f2bf(wb2.w);
            *(ushort8*)(&Wsh[row * F_BK + ps8]) = wv;
        }
        __syncthreads();
        #pragma unroll
        for (int kk = 0; kk < 2; ++kk) {
            const int psk = kk * 4 + lk8;
            short8 af[4], bfr[4];
            #pragma unroll
            for (int mf = 0; mf < 4; ++mf) {
                const int row = wm * 64 + mf * 16 + lr;
                af[mf] = *(const short8*)(&As[row * F_BK + ((psk ^ (row & 7)) * 8)]);
            }
            #pragma unroll
            for (int nf = 0; nf < 4; ++nf) {
                const int row = wn * 64 + nf * 16 + lr;
                bfr[nf] = *(const short8*)(&Wsh[row * F_BK + ((psk ^ (row & 7)) * 8)]);
            }
            #pragma unroll
            for (int mf = 0; mf < 4; ++mf)
                #pragma unroll
                for (int nf = 0; nf < 4; ++nf)
                    acc[mf][nf] = __builtin_amdgcn_mfma_f32_16x16x32_bf16(af[mf], bfr[nf], acc[mf][nf], 0, 0, 0);
        }
    }
    #pragma unroll
    for (int nf = 0; nf < 4; ++nf) {
        const int v = v0 + wn * 64 + nf * 16 + lr;
        const float bv = bias[v];
        #pragma unroll
        for (int mf = 0; mf < 4; ++mf) {
            const int mrow = m0 + wm * 64 + mf * 16 + (lane >> 4) * 4;
            #pragma unroll
            for (int j = 0; j < 4; ++j)
                out[(size_t)(mrow + j) * Vc + v] = acc[mf][nf][j] + bv;
        }
    }
}

extern "C" void kernel_launch(void* const* d_in, const int* in_sizes, int n_in,
                              void* d_out, int out_size, void* d_ws, size_t ws_size,
                              hipStream_t stream) {
    const float* x = (const float*)d_in[0];
    const float* y = (const float*)d_in[1];
    const float* W = (const float*)d_in[2];
    const float* b = (const float*)d_in[3];
    float* out = (float*)d_out;

    const size_t w_bytes = (size_t)Vc * Dc * sizeof(unsigned short);  // 1 MB
    if (ws_size >= w_bytes) {
        unsigned short* Wt = (unsigned short*)d_ws;
        cvt_wt<<<dim3((Vc * Dc / 8) / 256), 256, 0, stream>>>(W, Wt);
        joiner_v6<<<dim3((Bc * Tc * Uc / BM) * (Vc / BN)), BDIM, 0, stream>>>(x, y, Wt, b, out);
    } else {
        joiner_mfma<<<dim3(F_MT * F_NT), 256, 0, stream>>>(x, y, W, b, out);
    }
}